// Round 10
// baseline (646.470 us; speedup 1.0000x reference)
//
#include <hip/hip_runtime.h>
#include <math.h>

#define BB 2
#define CC 128
#define NN 4096
#define KK 16
#define DIMD 256
#define PHH 64
#define AHH 1024
#define EPSF 1e-5f
#define RSPLIT 256
#define RKCH ((BB * NN * KK) / RSPLIT)   // 512 samples per R block (single-pass S)
#define LSTR 258    // LDS row stride (halfwords): conflict-free transposed gathers
#define KNN_CAP 512

typedef unsigned short ushort_t;
typedef unsigned char uchar_t;
typedef unsigned long long u64;
typedef long long i64;
typedef __attribute__((ext_vector_type(8))) short short8;
typedef __attribute__((ext_vector_type(8))) unsigned short u16x8;
typedef __attribute__((ext_vector_type(4))) unsigned short u16x4;
typedef __attribute__((ext_vector_type(2))) unsigned short u16x2;
typedef __attribute__((ext_vector_type(4))) float f32x4;

__device__ __forceinline__ ushort_t f2b(float x) {
    union { float f; unsigned u; } v; v.f = x;
    unsigned r = v.u + 0x7fff + ((v.u >> 16) & 1);
    return (ushort_t)(r >> 16);
}
__device__ __forceinline__ float b2f(ushort_t x) {
    union { unsigned u; float f; } v; v.u = ((unsigned)x) << 16;
    return v.f;
}
__device__ __forceinline__ unsigned fsort(float x) {
    union { float f; unsigned u; } v; v.f = x;
    return v.u ^ ((v.u >> 31) ? 0xFFFFFFFFu : 0x80000000u);
}
__device__ __forceinline__ uchar_t f2f8(float x) {
    int p = __builtin_amdgcn_cvt_pk_fp8_f32(x, x, 0, false);
    return (uchar_t)(p & 0xFF);
}

#define GLDS16(gp, lp) __builtin_amdgcn_global_load_lds( \
    (const __attribute__((address_space(1))) void*)(gp), \
    (__attribute__((address_space(3))) void*)(lp), 16, 0, 0)

// ---------------- K0: zero scratch accumulators (only stats+mu; R is overwritten) ----
__global__ void zero_kernel(float* p, int n) {
    int i = blockIdx.x * blockDim.x + threadIdx.x;
    if (i < n) p[i] = 0.f;
}

// ---------------- K1: exact kNN via u64-key threshold select ----------------
__global__ __launch_bounds__(256) void knn_kernel(const float* __restrict__ pos,
                                                  int* __restrict__ idx) {
    int bid = blockIdx.x;
    int b = bid / NN, n = bid % NN;
    int t = threadIdx.x;
    int lane = t & 63, w = t >> 6;
    const float* px = pos + (size_t)b * 3 * NN;
    const float* py = px + NN;
    const float* pz = px + 2 * NN;
    float qx = px[n], qy = py[n], qz = pz[n];
    float qs = qx * qx + qy * qy + qz * qz;

    u64 keys[KK];
    u64 lmin = ~0ull;
#pragma unroll
    for (int j = 0; j < KK; ++j) {
        int m = t + 256 * j;
        float mx = px[m], my = py[m], mz = pz[m];
        float ms = mx * mx + my * my + mz * mz;
        float dt = qx * mx + qy * my + qz * mz;
        float d = qs + ms - 2.f * dt;
        u64 k = ((u64)fsort(d) << 32) | (unsigned)m;
        keys[j] = k;
        lmin = k < lmin ? k : lmin;
    }

    __shared__ u64 T0s[4];
    __shared__ u64 pool[KNN_CAP];
    __shared__ int cnt;

    u64 k = lmin, m4 = 0;
#pragma unroll
    for (int r = 0; r < 4; ++r) {
        u64 mv = k;
#pragma unroll
        for (int off = 32; off >= 1; off >>= 1) {
            u64 o = __shfl_xor(mv, off);
            mv = o < mv ? o : mv;
        }
        if (r == 3) m4 = mv;
        if (k == mv) k = ~0ull;
    }
    if (lane == 0) T0s[w] = m4;
    if (t == 0) cnt = 0;
    __syncthreads();
    u64 T0 = T0s[0];
    T0 = T0s[1] > T0 ? T0s[1] : T0;
    T0 = T0s[2] > T0 ? T0s[2] : T0;
    T0 = T0s[3] > T0 ? T0s[3] : T0;

#pragma unroll
    for (int j = 0; j < KK; ++j) {
        if (keys[j] <= T0) {
            int p = atomicAdd(&cnt, 1);
            if (p < KNN_CAP) pool[p] = keys[j];
        }
    }
    __syncthreads();
    int C = cnt < KNN_CAP ? cnt : KNN_CAP;
    if (t < C) {
        u64 me = pool[t];
        int r = 0;
        for (int i = 0; i < C; ++i) r += (pool[i] < me);
        if (r < KK) idx[(size_t)bid * KK + r] = (int)(me & 0xFFFFFFFFu);
    }
}

// ---------------- K2: transpose key/query -> kqT bf16 (8192 x 256) ----------------
__global__ __launch_bounds__(256) void cvtx_kernel(const float* __restrict__ key,
                                                   const float* __restrict__ query,
                                                   ushort_t* __restrict__ kqT) {
    __shared__ float xs[128][65];
    int b = blockIdx.y, n0 = blockIdx.x * 64, t = threadIdx.x;
    for (int h = 0; h < 2; ++h) {
        const float* src = (h ? query : key) + (size_t)b * CC * NN;
        if (h) __syncthreads();
#pragma unroll
        for (int it = 0; it < 32; ++it) {
            int l = it * 256 + t;
            xs[l >> 6][l & 63] = src[(size_t)(l >> 6) * NN + n0 + (l & 63)];
        }
        __syncthreads();
#pragma unroll
        for (int it = 0; it < 8; ++it) {
            int l = it * 256 + t;
            int row = l >> 5, c0 = (l & 31) * 4;
            u16x4 pk;
            pk[0] = f2b(xs[c0][row]);
            pk[1] = f2b(xs[c0 + 1][row]);
            pk[2] = f2b(xs[c0 + 2][row]);
            pk[3] = f2b(xs[c0 + 3][row]);
            *(u16x4*)(kqT + ((size_t)b * NN + n0 + row) * 256 + h * 128 + c0) = pk;
        }
    }
}

// ---------------- K3v: FUSED value chain — h1 -> value -> vT, one kernel ------
// 48KB LDS (hv16 overlays h1 then value; tile layout == GLDS layout -> bit-identical).
__global__ __launch_bounds__(256) void gemmvfull_kernel(const ushort_t* __restrict__ kqT,
                                                        const ushort_t* __restrict__ w1vb,
                                                        const ushort_t* __restrict__ wsvb,
                                                        const ushort_t* __restrict__ w2vb,
                                                        const ushort_t* __restrict__ wvb,
                                                        const float* __restrict__ b1,
                                                        const float* __restrict__ b2,
                                                        const float* __restrict__ bs,
                                                        const float* __restrict__ bv,
                                                        float* __restrict__ valueTf,
                                                        float* __restrict__ vT) {
    __shared__ ushort_t lA[128 * 32];
    __shared__ ushort_t lB[128 * 32];
    __shared__ ushort_t hv16[128 * 128];  // overlay: h1 (phases A/B), then value (B epi/C)
    int t = threadIdx.x, lane = t & 63, w = t >> 6;
    int wr = w >> 1, wc = w & 1;
    size_t row0 = (size_t)blockIdx.x * 128;
    int m16 = lane & 15, kg = lane >> 4;
    ushort_t* lA0 = lA + w * 512;
    ushort_t* lB0 = lB + w * 512;

    f32x4 acc[4][4];
#pragma unroll
    for (int i = 0; i < 4; ++i)
#pragma unroll
        for (int j = 0; j < 4; ++j) acc[i][j] = (f32x4){0.f, 0.f, 0.f, 0.f};

    // ---- phase A: h1 = relu(W1v·kq + b1), 128 rows x 128 ch, K=256 ----
    {
        const ushort_t* gA = kqT + (row0 + (size_t)w * 16 + m16) * 256 + kg * 8;
        const ushort_t* gB = w1vb + ((size_t)(w * 16 + m16)) * 256 + kg * 8;
        for (int kt = 0; kt < 8; ++kt) {
            int ko = kt * 32;
            GLDS16(gA + ko, lA0);
            GLDS16(gA + (size_t)64 * 256 + ko, lA0 + 2048);
            GLDS16(gB + ko, lB0);
            GLDS16(gB + (size_t)64 * 256 + ko, lB0 + 2048);
            __syncthreads();
            short8 af[4], bf[4];
#pragma unroll
            for (int i = 0; i < 4; ++i) {
                af[i] = *(const short8*)(lA + ((wr * 4 + i) * 512 + kg * 128 + m16 * 8));
                bf[i] = *(const short8*)(lB + ((wc * 4 + i) * 512 + kg * 128 + m16 * 8));
            }
#pragma unroll
            for (int i = 0; i < 4; ++i)
#pragma unroll
                for (int j = 0; j < 4; ++j)
                    acc[i][j] = __builtin_amdgcn_mfma_f32_16x16x32_bf16(af[i], bf[j], acc[i][j], 0, 0, 0);
            __syncthreads();
        }
#pragma unroll
        for (int j = 0; j < 4; ++j) {
            int c = wc * 64 + j * 16 + m16;
            float bi = b1[c];
            int win = c >> 5, cc = c & 31, kgp = cc >> 3, jp = cc & 7;
#pragma unroll
            for (int i = 0; i < 4; ++i) {
                int s = wr * 4 + i;
#pragma unroll
                for (int rg = 0; rg < 4; ++rg) {
                    int m16p = kg * 4 + rg;
                    hv16[win * 4096 + s * 512 + kgp * 128 + m16p * 8 + jp] =
                        f2b(fmaxf(acc[i][j][rg] + bi, 0.f));
                }
            }
        }
    }

    // ---- phase B: value = Ws·kq (K=256) + W2·h1 (K=128, LDS) + b2 + bs ----
#pragma unroll
    for (int i = 0; i < 4; ++i)
#pragma unroll
        for (int j = 0; j < 4; ++j) acc[i][j] = (f32x4){0.f, 0.f, 0.f, 0.f};
    {
        const ushort_t* gA = kqT + (row0 + (size_t)w * 16 + m16) * 256 + kg * 8;
        const ushort_t* gB = wsvb + ((size_t)(w * 16 + m16)) * 256 + kg * 8;
        for (int kt = 0; kt < 8; ++kt) {
            int ko = kt * 32;
            GLDS16(gA + ko, lA0);
            GLDS16(gA + (size_t)64 * 256 + ko, lA0 + 2048);
            GLDS16(gB + ko, lB0);
            GLDS16(gB + (size_t)64 * 256 + ko, lB0 + 2048);
            __syncthreads();
            short8 af[4], bf[4];
#pragma unroll
            for (int i = 0; i < 4; ++i) {
                af[i] = *(const short8*)(lA + ((wr * 4 + i) * 512 + kg * 128 + m16 * 8));
                bf[i] = *(const short8*)(lB + ((wc * 4 + i) * 512 + kg * 128 + m16 * 8));
            }
#pragma unroll
            for (int i = 0; i < 4; ++i)
#pragma unroll
                for (int j = 0; j < 4; ++j)
                    acc[i][j] = __builtin_amdgcn_mfma_f32_16x16x32_bf16(af[i], bf[j], acc[i][j], 0, 0, 0);
            __syncthreads();
        }
    }
    {
        const ushort_t* gB = w2vb + ((size_t)(w * 16 + m16)) * 128 + kg * 8;
        for (int kt = 0; kt < 4; ++kt) {
            int ko = kt * 32;
            GLDS16(gB + ko, lB0);
            GLDS16(gB + (size_t)64 * 128 + ko, lB0 + 2048);
            __syncthreads();
            short8 af[4], bf[4];
#pragma unroll
            for (int i = 0; i < 4; ++i) {
                af[i] = *(const short8*)(hv16 + (kt * 4096 + (wr * 4 + i) * 512 + kg * 128 + m16 * 8));
                bf[i] = *(const short8*)(lB + ((wc * 4 + i) * 512 + kg * 128 + m16 * 8));
            }
#pragma unroll
            for (int i = 0; i < 4; ++i)
#pragma unroll
                for (int j = 0; j < 4; ++j)
                    acc[i][j] = __builtin_amdgcn_mfma_f32_16x16x32_bf16(af[i], bf[j], acc[i][j], 0, 0, 0);
            __syncthreads();   // after the last iteration: ALL h1 reads drained
        }
    }
#pragma unroll
    for (int j = 0; j < 4; ++j) {
        int c = wc * 64 + j * 16 + m16;
        float bi = b2[c] + bs[c];
        int win = c >> 5, cc = c & 31, kgp = cc >> 3, jp = cc & 7;
#pragma unroll
        for (int i = 0; i < 4; ++i) {
            int s = wr * 4 + i;
#pragma unroll
            for (int rg = 0; rg < 4; ++rg) {
                float v = acc[i][j][rg] + bi;
                int m16p = kg * 4 + rg;
                valueTf[(row0 + s * 16 + m16p) * (size_t)CC + c] = v;
                hv16[win * 4096 + s * 512 + kgp * 128 + m16p * 8 + jp] = f2b(v);
            }
        }
    }
    __syncthreads();

    // ---- phase C: vT = value·wv^T + bv, two 128-col passes, K=128 (LDS) ----
    for (int pass = 0; pass < 2; ++pass) {
#pragma unroll
        for (int i = 0; i < 4; ++i)
#pragma unroll
            for (int j = 0; j < 4; ++j) acc[i][j] = (f32x4){0.f, 0.f, 0.f, 0.f};
        int col0 = pass * 128;
        const ushort_t* gB = wvb + ((size_t)(col0 + w * 16 + m16)) * 128 + kg * 8;
        for (int kt = 0; kt < 4; ++kt) {
            int ko = kt * 32;
            GLDS16(gB + ko, lB0);
            GLDS16(gB + (size_t)64 * 128 + ko, lB0 + 2048);
            __syncthreads();
            short8 af[4], bf[4];
#pragma unroll
            for (int i = 0; i < 4; ++i) {
                af[i] = *(const short8*)(hv16 + (kt * 4096 + (wr * 4 + i) * 512 + kg * 128 + m16 * 8));
                bf[i] = *(const short8*)(lB + ((wc * 4 + i) * 512 + kg * 128 + m16 * 8));
            }
#pragma unroll
            for (int i = 0; i < 4; ++i)
#pragma unroll
                for (int j = 0; j < 4; ++j)
                    acc[i][j] = __builtin_amdgcn_mfma_f32_16x16x32_bf16(af[i], bf[j], acc[i][j], 0, 0, 0);
            __syncthreads();
        }
#pragma unroll
        for (int j = 0; j < 4; ++j) {
            int n = col0 + wc * 64 + j * 16 + m16;
            float bi = bv[n];
#pragma unroll
            for (int i = 0; i < 4; ++i) {
                size_t r = row0 + wr * 64 + i * 16 + kg * 4;
#pragma unroll
                for (int rg = 0; rg < 4; ++rg)
                    vT[(r + rg) * (size_t)DIMD + n] = acc[i][j][rg] + bi;
            }
        }
    }
}

// ---------------- K3c: kT and qT in one launch ----------------
__global__ __launch_bounds__(256) void gemmkq_kernel(const ushort_t* __restrict__ kqT,
                                                     const ushort_t* __restrict__ wkb,
                                                     const ushort_t* __restrict__ wqb,
                                                     const float* __restrict__ bk,
                                                     const float* __restrict__ bq,
                                                     float* __restrict__ kT,
                                                     float* __restrict__ qT) {
    __shared__ ushort_t lA[128 * 32];
    __shared__ ushort_t lB[128 * 32];
    int half = blockIdx.y >> 1;
    int col0 = (blockIdx.y & 1) * 128;
    const ushort_t* A = kqT + half * 128;
    const ushort_t* Bm = half ? wqb : wkb;
    const float* bias = half ? bq : bk;
    float* outF = half ? qT : kT;

    int t = threadIdx.x, lane = t & 63, w = t >> 6;
    int wr = w >> 1, wc = w & 1;
    size_t row0 = (size_t)blockIdx.x * 128;
    int m16 = lane & 15, kg = lane >> 4;
    f32x4 acc[4][4];
#pragma unroll
    for (int i = 0; i < 4; ++i)
#pragma unroll
        for (int j = 0; j < 4; ++j) acc[i][j] = (f32x4){0.f, 0.f, 0.f, 0.f};
    const ushort_t* gA = A + (row0 + (size_t)w * 16 + m16) * 256 + kg * 8;
    const ushort_t* gB = Bm + ((size_t)(col0 + w * 16 + m16)) * 128 + kg * 8;
    ushort_t* lA0 = lA + w * 512;
    ushort_t* lB0 = lB + w * 512;
    for (int kt = 0; kt < 4; ++kt) {
        int ko = kt * 32;
        GLDS16(gA + ko, lA0);
        GLDS16(gA + (size_t)64 * 256 + ko, lA0 + 2048);
        GLDS16(gB + ko, lB0);
        GLDS16(gB + (size_t)64 * 128 + ko, lB0 + 2048);
        __syncthreads();
        short8 af[4], bf[4];
#pragma unroll
        for (int i = 0; i < 4; ++i) {
            af[i] = *(const short8*)(lA + ((wr * 4 + i) * 512 + kg * 128 + m16 * 8));
            bf[i] = *(const short8*)(lB + ((wc * 4 + i) * 512 + kg * 128 + m16 * 8));
        }
#pragma unroll
        for (int i = 0; i < 4; ++i)
#pragma unroll
            for (int j = 0; j < 4; ++j)
                acc[i][j] = __builtin_amdgcn_mfma_f32_16x16x32_bf16(af[i], bf[j], acc[i][j], 0, 0, 0);
        __syncthreads();
    }
#pragma unroll
    for (int j = 0; j < 4; ++j) {
        int n = col0 + wc * 64 + j * 16 + m16;
        float bi = bias[n];
#pragma unroll
        for (int i = 0; i < 4; ++i) {
            size_t r = row0 + wr * 64 + i * 16 + kg * 4;
#pragma unroll
            for (int rg = 0; rg < 4; ++rg)
                outF[(r + rg) * (size_t)DIMD + n] = acc[i][j][rg] + bi;
        }
    }
}

// ---------------- K5: pos_rel moments (wave-shfl reduce; 1 barrier) ----
__global__ __launch_bounds__(256) void pos_stats_kernel(const float* __restrict__ pos,
                                                        const int* __restrict__ idx,
                                                        float* __restrict__ stats) {
    int sid = blockIdx.x * 256 + threadIdx.x;
    int b = sid / (NN * KK);
    int r = sid % (NN * KK);
    int n = r / KK;
    int m = idx[sid];
    const float* px = pos + (size_t)b * 3 * NN;
    float dx = px[n] - px[m];
    float dy = px[NN + n] - px[NN + m];
    float dz = px[2 * NN + n] - px[2 * NN + m];
    float v[9] = {dx, dy, dz, dx * dx, dy * dy, dz * dz, dx * dy, dx * dz, dy * dz};
    __shared__ float lsum[4][9];
    int lane = threadIdx.x & 63, w = threadIdx.x >> 6;
#pragma unroll
    for (int j = 0; j < 9; ++j) {
        float x = v[j];
#pragma unroll
        for (int off = 32; off >= 1; off >>= 1) x += __shfl_xor(x, off);
        if (lane == 0) lsum[w][j] = x;
    }
    __syncthreads();
    if (threadIdx.x < 9) {
        float s = lsum[0][threadIdx.x] + lsum[1][threadIdx.x]
                + lsum[2][threadIdx.x] + lsum[3][threadIdx.x];
        atomicAdd(&stats[threadIdx.x], s);
    }
}

// ---------------- K6: pos BN affine (a1, a0) per 64 channels ----------------
__global__ void pos_bn_kernel(const float* __restrict__ stats, const float* __restrict__ pw1,
                              const float* __restrict__ pb1, const float* __restrict__ pg1,
                              const float* __restrict__ pbe1, float* __restrict__ posA) {
    int c = threadIdx.x;
    if (c >= PHH) return;
    float M = (float)(BB * NN * KK);
    float mu0 = stats[0] / M, mu1 = stats[1] / M, mu2 = stats[2] / M;
    float E00 = stats[3] / M, E11 = stats[4] / M, E22 = stats[5] / M;
    float E01 = stats[6] / M, E02 = stats[7] / M, E12 = stats[8] / M;
    float w0 = pw1[c * 3], w1 = pw1[c * 3 + 1], w2 = pw1[c * 3 + 2];
    float wmu = w0 * mu0 + w1 * mu1 + w2 * mu2;
    float mean_h = wmu + pb1[c];
    float Eh2 = w0 * w0 * E00 + w1 * w1 * E11 + w2 * w2 * E22
              + 2.f * (w0 * w1 * E01 + w0 * w2 * E02 + w1 * w2 * E12)
              + 2.f * pb1[c] * wmu + pb1[c] * pb1[c];
    float var = Eh2 - mean_h * mean_h;
    float a1 = pg1[c] * rsqrtf(var + EPSF);
    posA[c] = a1;
    posA[PHH + c] = pbe1[c] - mean_h * a1;
}

// ---------------- K9: R partials via MFMA (1024 thr, single-pass S, mu folded) ----
__global__ __launch_bounds__(1024) void rg_kernel(const ushort_t* __restrict__ S,
                                                  float* __restrict__ Rpart,
                                                  float* __restrict__ mu) {
    __shared__ ushort_t ls[32 * LSTR];
    __shared__ float fmu[DIMD];
    int t = threadIdx.x;
    int lane = t & 63, w = t >> 6;          // w 0..15
    int ti = w >> 3, tj = (w >> 2) & 1;     // quadrant
    int wr = (w >> 1) & 1, wc = w & 1;
    int m16 = lane & 15, kg = lane >> 4;
    size_t kbase = (size_t)blockIdx.x * RKCH;

    if (t < DIMD) fmu[t] = 0.f;

    f32x4 acc[4][4];
#pragma unroll
    for (int i = 0; i < 4; ++i)
#pragma unroll
        for (int j = 0; j < 4; ++j) acc[i][j] = (f32x4){0.f, 0.f, 0.f, 0.f};

    int lm = t >> 5;            // 0..31: k-row within chunk
    int lc = (t & 31) * 8;      // 8-chan octet
    const ushort_t* gS = S + (kbase + lm) * DIMD + lc;
    ushort_t* lp = ls + lm * LSTR + lc;
    float csum[8];
#pragma unroll
    for (int c = 0; c < 8; ++c) csum[c] = 0.f;

    for (int kt = 0; kt < RKCH / 32; ++kt) {
        u16x8 v = *(const u16x8*)(gS + (size_t)kt * 32 * DIMD);
        __syncthreads();
#pragma unroll
        for (int q = 0; q < 4; ++q)
            *(u16x2*)(lp + 2 * q) = (u16x2){v[2 * q], v[2 * q + 1]};
#pragma unroll
        for (int c = 0; c < 8; ++c) csum[c] += b2f(v[c]);
        __syncthreads();
        short8 af[4], bf[4];
#pragma unroll
        for (int i = 0; i < 4; ++i) {
            int chA = ti * 128 + wr * 64 + i * 16 + m16;
            int chB = tj * 128 + wc * 64 + i * 16 + m16;
#pragma unroll
            for (int j = 0; j < 8; ++j) {
                int k = kg * 8 + j;
                af[i][j] = (short)ls[k * LSTR + chA];
                bf[i][j] = (short)ls[k * LSTR + chB];
            }
        }
#pragma unroll
        for (int i = 0; i < 4; ++i)
#pragma unroll
            for (int j = 0; j < 4; ++j)
                acc[i][j] = __builtin_amdgcn_mfma_f32_16x16x32_bf16(af[i], bf[j], acc[i][j], 0, 0, 0);
    }

    float* rp = Rpart + (size_t)blockIdx.x * (DIMD * DIMD);
#pragma unroll
    for (int i = 0; i < 4; ++i) {
        int r0 = ti * 128 + wr * 64 + i * 16 + kg * 4;
#pragma unroll
        for (int j = 0; j < 4; ++j) {
            int cn = tj * 128 + wc * 64 + j * 16 + m16;
#pragma unroll
            for (int rg = 0; rg < 4; ++rg)
                rp[(size_t)(r0 + rg) * DIMD + cn] = acc[i][j][rg];
        }
    }

    __syncthreads();
#pragma unroll
    for (int c = 0; c < 8; ++c) atomicAdd(&fmu[lc + c], csum[c]);
    __syncthreads();
    if (t < DIMD) atomicAdd(&mu[t], fmu[t]);
}

// ---------------- K9b: reduce R partials ----------------
__global__ __launch_bounds__(256) void r_reduce_kernel(const float* __restrict__ Rpart,
                                                       float* __restrict__ R) {
    int e = blockIdx.x * 256 + threadIdx.x;
    float s = 0.f;
    for (int p = 0; p < RSPLIT; ++p) s += Rpart[(size_t)p * (DIMD * DIMD) + e];
    R[e] = s;
}

// ---------------- K10: attn BN -> fused scale/offset per hidden channel ----------------
__global__ __launch_bounds__(256) void attn_bn_kernel(const float* __restrict__ R,
                                                      const float* __restrict__ mu,
                                                      const float* __restrict__ aw1,
                                                      const float* __restrict__ ab1,
                                                      const float* __restrict__ ag1,
                                                      const float* __restrict__ abe1,
                                                      float* __restrict__ attA) {
    int c = blockIdx.x;
    int t = threadIdx.x;
    __shared__ float wsh[DIMD];
    __shared__ float red[DIMD];
    wsh[t] = aw1[(size_t)c * DIMD + t];
    __syncthreads();
    const float* Rr = R + (size_t)t * DIMD;
    float q = 0.f;
#pragma unroll 4
    for (int j = 0; j < DIMD; ++j) q += Rr[j] * wsh[j];
    red[t] = q * wsh[t];
    __syncthreads();
    for (int off = 128; off >= 1; off >>= 1) {
        if (t < off) red[t] += red[t + off];
        __syncthreads();
    }
    float wRw = red[0];
    __syncthreads();
    red[t] = wsh[t] * mu[t];
    __syncthreads();
    for (int off = 128; off >= 1; off >>= 1) {
        if (t < off) red[t] += red[t + off];
        __syncthreads();
    }
    if (t == 0) {
        float M = (float)(BB * NN * KK);
        float wmu = red[0] / M;
        float b1c = ab1[c];
        float Eh = wmu + b1c;
        float Eh2 = wRw / M + 2.f * b1c * wmu + b1c * b1c;
        float var = Eh2 - Eh * Eh;
        float a1 = ag1[c] * rsqrtf(var + EPSF);
        attA[c] = a1;
        attA[AHH + c] = a1 * b1c + abe1[c] - Eh * a1;
    }
}

// ---------------- K10b: convert all weights to bf16 (+ W2 to fp8 x64) ----------------
__global__ void cvt_w_kernel(const float* __restrict__ aw1, const float* __restrict__ aw2,
                             const float* __restrict__ pw2,
                             const float* __restrict__ mw1, const float* __restrict__ mws,
                             const float* __restrict__ mw2,
                             const float* __restrict__ wk, const float* __restrict__ wq,
                             const float* __restrict__ wv,
                             ushort_t* __restrict__ w1b, ushort_t* __restrict__ w2b,
                             ushort_t* __restrict__ pw2b,
                             ushort_t* __restrict__ w1vb, ushort_t* __restrict__ wsvb,
                             ushort_t* __restrict__ w2vb,
                             ushort_t* __restrict__ wkb, ushort_t* __restrict__ wqb,
                             ushort_t* __restrict__ wvb,
                             uchar_t* __restrict__ w2f8) {
    int i = blockIdx.x * 256 + threadIdx.x;
    int o = i;
    if (o < 262144) { w1b[o] = f2b(aw1[o]); return; }   o -= 262144;
    if (o < 262144) { w2b[o] = f2b(aw2[o]); w2f8[o] = f2f8(aw2[o] * 64.f); return; } o -= 262144;
    if (o < 16384)  { pw2b[o] = f2b(pw2[o]); return; }  o -= 16384;
    if (o < 32768)  { w1vb[o] = f2b(mw1[o]); return; }  o -= 32768;
    if (o < 32768)  { wsvb[o] = f2b(mws[o]); return; }  o -= 32768;
    if (o < 16384)  { w2vb[o] = f2b(mw2[o]); return; }  o -= 16384;
    if (o < 32768)  { wkb[o] = f2b(wk[o]); return; }    o -= 32768;
    if (o < 32768)  { wqb[o] = f2b(wq[o]); return; }    o -= 32768;
    if (o < 32768)  { wvb[o] = f2b(wv[o]); }
}

// ---------------- gemmS: s = q - k_g + (P1·pw2^T + pb2), P1 fused in-staging ----------
__global__ __launch_bounds__(256) void gemmS_kernel(const float* __restrict__ pos,
                                                    const int* __restrict__ gidx,
                                                    const float* __restrict__ pw1,
                                                    const float* __restrict__ pb1,
                                                    const float* __restrict__ posA,
                                                    const ushort_t* __restrict__ Bm,
                                                    const float* __restrict__ p0,
                                                    ushort_t* __restrict__ Sb,
                                                    const float* __restrict__ qT,
                                                    const float* __restrict__ kT) {
    __shared__ ushort_t lA[128 * 32];
    __shared__ ushort_t lB[128 * 32];
    __shared__ float ld3[128][4];    // dx,dy,dz per row (pad 4 for bank spread)
    __shared__ float pc[64][6];      // w0,w1,w2,b1,a1,a0 per hidden channel
    int t = threadIdx.x;
    int lane = t & 63, w = t >> 6;
    int wr = w >> 1, wc = w & 1;
    size_t row0 = (size_t)blockIdx.x * 128;
    int col0 = blockIdx.y * 128;
    int m16 = lane & 15, kg = lane >> 4;

    if (t < 64) {
        pc[t][0] = pw1[t * 3]; pc[t][1] = pw1[t * 3 + 1]; pc[t][2] = pw1[t * 3 + 2];
        pc[t][3] = pb1[t];     pc[t][4] = posA[t];        pc[t][5] = posA[PHH + t];
    }
    if (t < 128) {
        int row = (int)row0 + t;
        int m = gidx[row];
        int p = row >> 4;
        int b = p >> 12, n = p & (NN - 1);
        const float* px = pos + (size_t)b * 3 * NN;
        ld3[t][0] = px[n] - px[m];
        ld3[t][1] = px[NN + n] - px[NN + m];
        ld3[t][2] = px[2 * NN + n] - px[2 * NN + m];
    }

    f32x4 acc[4][4];
#pragma unroll
    for (int i = 0; i < 4; ++i)
#pragma unroll
        for (int j = 0; j < 4; ++j) acc[i][j] = (f32x4){0.f, 0.f, 0.f, 0.f};

    const ushort_t* gB = Bm + ((size_t)(col0 + w * 16 + m16)) * PHH + kg * 8;
    ushort_t* lB0 = lB + w * 512;
    __syncthreads();   // ld3/pc ready

    for (int kt = 0; kt < 2; ++kt) {
        int ko = kt * 32;
        GLDS16(gB + ko, lB0);
        GLDS16(gB + (size_t)64 * PHH + ko, lB0 + 2048);
#pragma unroll
        for (int half = 0; half < 2; ++half) {
            int rl = half * 64 + w * 16 + m16;
            float dx = ld3[rl][0], dy = ld3[rl][1], dz = ld3[rl][2];
            u16x8 pk;
#pragma unroll
            for (int j = 0; j < 8; ++j) {
                int c = ko + kg * 8 + j;
                float h = pc[c][0] * dx + pc[c][1] * dy + pc[c][2] * dz + pc[c][3];
                pk[j] = f2b(fmaxf(h * pc[c][4] + pc[c][5], 0.f));
            }
            *(u16x8*)(lA + w * 512 + half * 2048 + lane * 8) = pk;
        }
        __syncthreads();
        short8 af[4], bf[4];
#pragma unroll
        for (int i = 0; i < 4; ++i) {
            af[i] = *(const short8*)(lA + ((wr * 4 + i) * 512 + kg * 128 + m16 * 8));
            bf[i] = *(const short8*)(lB + ((wc * 4 + i) * 512 + kg * 128 + m16 * 8));
        }
#pragma unroll
        for (int i = 0; i < 4; ++i)
#pragma unroll
            for (int j = 0; j < 4; ++j)
                acc[i][j] = __builtin_amdgcn_mfma_f32_16x16x32_bf16(af[i], bf[j], acc[i][j], 0, 0, 0);
        __syncthreads();
    }

    int nn[4]; float bi[4];
#pragma unroll
    for (int j = 0; j < 4; ++j) { nn[j] = col0 + wc * 64 + j * 16 + m16; bi[j] = p0[nn[j]]; }
#pragma unroll
    for (int i = 0; i < 4; ++i) {
        size_t r = row0 + wr * 64 + i * 16 + kg * 4;
#pragma unroll
        for (int rg = 0; rg < 4; ++rg) {
            size_t rr = r + rg;
            int p = (int)(rr >> 4);
            int krow = (p & ~(NN - 1)) + gidx[rr];
            const float* qrow = qT + (size_t)p * DIMD;
            const float* kro = kT + (size_t)krow * DIMD;
#pragma unroll
            for (int j = 0; j < 4; ++j) {
                float sv = qrow[nn[j]] - kro[nn[j]] + acc[i][j][rg] + bi[j];
                Sb[rr * (size_t)DIMD + nn[j]] = f2b(sv);
            }
        }
    }
}

// ---------------- K11: fused attn MLP + softmax + agg + FINAL (R10) --------
// jc loop frozen (7 structural nulls). R10: final_kernel folded into the
// epilogue (R5 ablation: this kernel absorbs epilogue work nearly free).
// agg -> lAg (4KB LDS at smem+36864, above lgB's 36848B) -> y = we·agg + be
// + valueTf, stored directly to out. Identical float4 accumulation order as
// final_kernel -> bit-identical output. Deletes final launch + aggT 16MB RT.
__global__ __launch_bounds__(256, 3) void fused_mlp_kernel(const ushort_t* __restrict__ S,
                                                        const ushort_t* __restrict__ w1b,
                                                        const uchar_t* __restrict__ w2f8,
                                                        const float* __restrict__ attA,
                                                        const float* __restrict__ ab2,
                                                        const int* __restrict__ idx,
                                                        const float* __restrict__ qT,
                                                        const float* __restrict__ kT,
                                                        const float* __restrict__ vT,
                                                        const float* __restrict__ we,
                                                        const float* __restrict__ be,
                                                        const float* __restrict__ valueTf,
                                                        float* __restrict__ out) {
    __shared__ char smem[49152];
    ushort_t* lS  = (ushort_t*)smem;             // 32 KB: 64 smp x 256 k bf16
    uchar_t*  lHt = (uchar_t*)(smem + 32768);    // 2 x 8 KB: 128 hid x 64 smp fp8, dbuf
    ushort_t* lgB = (ushort_t*)smem;             // epilogue overlay: 256 out x 64 smp, stride 72
    float*    lAg = (float*)(smem + 36864);      // 4 KB: agg[pt][256], above lgB

    int t = threadIdx.x;
    int lane = t & 63, w = t >> 6;
    int m16 = lane & 15, kg = lane >> 4;
    size_t row0 = (size_t)blockIdx.x * 64;

#pragma unroll
    for (int i = 0; i < 8; ++i) {
        int lb = w * 8 + i;
        int kt = lb >> 2, st = lb & 3;
        const ushort_t* gp = S + (row0 + st * 16 + m16) * DIMD + kt * 32 + kg * 8;
        GLDS16(gp, lS + lb * 512);
    }

    f32x4 acc2[4][4];
#pragma unroll
    for (int i = 0; i < 4; ++i)
#pragma unroll
        for (int j = 0; j < 4; ++j) acc2[i][j] = (f32x4){0.f, 0.f, 0.f, 0.f};

    __syncthreads();

    for (int jc = 0; jc < 8; ++jc) {
        uchar_t* lHb = lHt + (jc & 1) * 8192;
        f32x4 acc1[2][4];
#pragma unroll
        for (int hi = 0; hi < 2; ++hi)
#pragma unroll
            for (int sj = 0; sj < 4; ++sj) acc1[hi][sj] = (f32x4){0.f, 0.f, 0.f, 0.f};
        const ushort_t* wrow = w1b + ((size_t)(jc * 128 + w * 32 + m16)) * DIMD + kg * 8;
#pragma unroll
        for (int kt = 0; kt < 8; ++kt) {
            short8 af[2], bf[4];
            af[0] = *(const short8*)(wrow + kt * 32);
            af[1] = *(const short8*)(wrow + (size_t)16 * DIMD + kt * 32);
#pragma unroll
            for (int sj = 0; sj < 4; ++sj)
                bf[sj] = *(const short8*)(lS + (kt * 4 + sj) * 512 + kg * 128 + m16 * 8);
            __builtin_amdgcn_s_setprio(1);
#pragma unroll
            for (int hi = 0; hi < 2; ++hi)
#pragma unroll
                for (int sj = 0; sj < 4; ++sj)
                    acc1[hi][sj] = __builtin_amdgcn_mfma_f32_16x16x32_bf16(af[hi], bf[sj], acc1[hi][sj], 0, 0, 0);
            __builtin_amdgcn_s_setprio(0);
        }
#pragma unroll
        for (int hi = 0; hi < 2; ++hi) {
            float4 sc4 = *(const float4*)(attA + jc * 128 + w * 32 + hi * 16 + kg * 4);
            float4 of4 = *(const float4*)(attA + AHH + jc * 128 + w * 32 + hi * 16 + kg * 4);
#pragma unroll
            for (int sj = 0; sj < 4; ++sj) {
                float h0 = fmaxf(sc4.x * acc1[hi][sj][0] + of4.x, 0.f);
                float h1 = fmaxf(sc4.y * acc1[hi][sj][1] + of4.y, 0.f);
                float h2 = fmaxf(sc4.z * acc1[hi][sj][2] + of4.z, 0.f);
                float h3 = fmaxf(sc4.w * acc1[hi][sj][3] + of4.w, 0.f);
                int p01 = __builtin_amdgcn_cvt_pk_fp8_f32(h0, h1, 0, false);
                int pk = __builtin_amdgcn_cvt_pk_fp8_f32(h2, h3, p01, true);
                int ah = (w * 4 + sj) * 512 + (hi * 2 + (kg >> 1)) * 128 + m16 * 8 + (kg & 1) * 4;
                *(int*)(lHb + ah) = pk;
            }
        }
        __syncthreads();
#pragma unroll
        for (int gh = 0; gh < 2; ++gh) {
            i64 af2[8];
#pragma unroll
            for (int gq = 0; gq < 2; ++gq)
#pragma unroll
                for (int oi = 0; oi < 4; ++oi)
                    af2[gq * 4 + oi] = *(const i64*)(w2f8 + ((size_t)(w * 64 + oi * 16 + m16)) * AHH + jc * 128 + (gh * 2 + gq) * 32 + kg * 8);
#pragma unroll
            for (int gq = 0; gq < 2; ++gq) {
                i64 bf2[4];
#pragma unroll
                for (int sj = 0; sj < 4; ++sj)
                    bf2[sj] = *(const i64*)(lHb + ((gh * 2 + gq) * 4 + sj) * 512 + kg * 128 + m16 * 8);
                __builtin_amdgcn_s_setprio(1);
#pragma unroll
                for (int oi = 0; oi < 4; ++oi)
#pragma unroll
                    for (int sj = 0; sj < 4; ++sj)
                        acc2[oi][sj] = __builtin_amdgcn_mfma_f32_16x16x32_fp8_fp8(af2[gq * 4 + oi], bf2[sj], acc2[oi][sj], 0, 0, 0);
                __builtin_amdgcn_s_setprio(0);
            }
        }
    }
    __syncthreads();

    // phase 1: logits (acc2/64 + b2) -> lgB[out][smp] (bf16, stride 72)
    const float invsc = 0.015625f;
#pragma unroll
    for (int oi = 0; oi < 4; ++oi) {
        int ob = w * 64 + oi * 16 + kg * 4;
        float4 b2v = *(const float4*)(ab2 + ob);
#pragma unroll
        for (int sj = 0; sj < 4; ++sj) {
            int smp = sj * 16 + m16;
            lgB[(ob + 0) * 72 + smp] = f2b(acc2[oi][sj][0] * invsc + b2v.x);
            lgB[(ob + 1) * 72 + smp] = f2b(acc2[oi][sj][1] * invsc + b2v.y);
            lgB[(ob + 2) * 72 + smp] = f2b(acc2[oi][sj][2] * invsc + b2v.z);
            lgB[(ob + 3) * 72 + smp] = f2b(acc2[oi][sj][3] * invsc + b2v.w);
        }
    }
    __syncthreads();

    // phase 2: thread t owns out-channel t; 4 points; agg -> lAg (LDS)
    {
        int outc = t;
        for (int pt = 0; pt < 4; ++pt) {
            int pid = (int)(row0 >> 4) + pt;
            u16x8 v0 = *(const u16x8*)(lgB + outc * 72 + pt * 16);
            u16x8 v1 = *(const u16x8*)(lgB + outc * 72 + pt * 16 + 8);
            float lg[KK];
#pragma unroll
            for (int s = 0; s < 8; ++s) { lg[s] = b2f(v0[s]); lg[s + 8] = b2f(v1[s]); }
            float mx = lg[0];
#pragma unroll
            for (int s = 1; s < KK; ++s) mx = fmaxf(mx, lg[s]);
            float se = 0.f;
#pragma unroll
            for (int s = 0; s < KK; ++s) { lg[s] = expf(lg[s] - mx); se += lg[s]; }
            float inv = 1.f / se;
            int base = pid & ~(NN - 1);
            float acc = 0.f;
#pragma unroll
            for (int s = 0; s < KK; ++s) {
                int row = pid * KK + s;
                int krow = base + idx[row];
                float sv = b2f(S[(size_t)row * DIMD + outc]);
                float kv = kT[(size_t)krow * DIMD + outc];
                acc += lg[s] * (sv + kv);
            }
            float vf = vT[(size_t)pid * DIMD + outc];
            float q  = qT[(size_t)pid * DIMD + outc];
            lAg[pt * DIMD + outc] = vf - q + acc * inv;
        }
    }
    __syncthreads();

    // phase 3 (R10): y = we·agg + be + valueTf -> out, fused (was final_kernel)
    {
        int o = t & 127, hf = t >> 7;
        const float4* wrp = (const float4*)(we + (size_t)o * DIMD);
        const float* g0 = lAg + (hf * 2) * DIMD;
        const float* g1 = lAg + (hf * 2 + 1) * DIMD;
        float a0 = 0.f, a1 = 0.f;
#pragma unroll 8
        for (int i4 = 0; i4 < DIMD / 4; ++i4) {
            float4 w4 = wrp[i4];
            float4 x0 = *(const float4*)(g0 + i4 * 4);
            float4 x1 = *(const float4*)(g1 + i4 * 4);
            a0 += w4.x * x0.x + w4.y * x0.y + w4.z * x0.z + w4.w * x0.w;
            a1 += w4.x * x1.x + w4.y * x1.y + w4.z * x1.z + w4.w * x1.w;
        }
        float bo = be[o];
        int pid0 = (int)(row0 >> 4);
#pragma unroll
        for (int pp = 0; pp < 2; ++pp) {
            int pt = hf * 2 + pp;
            int pid = pid0 + pt;
            int b = pid >> 12, n = pid & (NN - 1);
            float vv = valueTf[(size_t)pid * CC + o];
            out[((size_t)b * CC + o) * NN + n] = (pp ? a1 : a0) + bo + vv;
        }
    }
}

extern "C" void kernel_launch(void* const* d_in, const int* in_sizes, int n_in,
                              void* d_out, int out_size, void* d_ws, size_t ws_size,
                              hipStream_t stream) {
    (void)in_sizes; (void)n_in; (void)out_size; (void)ws_size;
    const float* pos     = (const float*)d_in[0];
    const float* key     = (const float*)d_in[1];
    const float* query   = (const float*)d_in[2];
    const float* mlpv_w1 = (const float*)d_in[3];
    const float* mlpv_b1 = (const float*)d_in[4];
    const float* mlpv_w2 = (const float*)d_in[5];
    const float* mlpv_b2 = (const float*)d_in[6];
    const float* mlpv_ws = (const float*)d_in[7];
    const float* mlpv_bs = (const float*)d_in[8];
    const float* wk  = (const float*)d_in[9];
    const float* bk  = (const float*)d_in[10];
    const float* wq  = (const float*)d_in[11];
    const float* bq  = (const float*)d_in[12];
    const float* wv  = (const float*)d_in[13];
    const float* bv  = (const float*)d_in[14];
    const float* pw1 = (const float*)d_in[15];
    const float* pb1 = (const float*)d_in[16];
    const float* pg1 = (const float*)d_in[17];
    const float* pbe1= (const float*)d_in[18];
    const float* pw2 = (const float*)d_in[19];
    const float* pb2 = (const float*)d_in[20];
    const float* aw1 = (const float*)d_in[21];
    const float* ab1 = (const float*)d_in[22];
    const float* ag1 = (const float*)d_in[23];
    const float* abe1= (const float*)d_in[24];
    const float* aw2 = (const float*)d_in[25];
    const float* ab2 = (const float*)d_in[26];
    const float* we  = (const float*)d_in[27];
    const float* be  = (const float*)d_in[28];
    float* out = (float*)d_out;

    char* wsb = (char*)d_ws;
    size_t off = 0;
    auto alloc = [&](size_t bytes) {
        void* p = wsb + off;
        off += (bytes + 255) & ~(size_t)255;
        return p;
    };
    const size_t M = (size_t)BB * NN * KK;   // 131072 rows
    const size_t P = (size_t)BB * NN;        // 8192 points
    int*   idx   = (int*)  alloc(M * 4);
    ushort_t* kqT     = (ushort_t*)alloc(P * 256 * 2);
    float*    valueTf = (float*)   alloc(P * CC * 4);
    float* kT    = (float*)alloc(P * DIMD * 4);
    float* qT    = (float*)alloc(P * DIMD * 4);
    float* vT    = (float*)alloc(P * DIMD * 4);
    float* zero0 = (float*)alloc((size_t)(16 + 256 + 65536) * 4);
    float* stats = zero0;
    float* mu    = zero0 + 16;
    float* R     = zero0 + 16 + 256;
    float* posA  = (float*)alloc((size_t)2 * PHH * 4);
    float* attA  = (float*)alloc((size_t)2 * AHH * 4);
    ushort_t* w1b  = (ushort_t*)alloc((size_t)AHH * DIMD * 2);
    ushort_t* w2b  = (ushort_t*)alloc((size_t)DIMD * AHH * 2);
    uchar_t*  w2f8 = (uchar_t*) alloc((size_t)DIMD * AHH);
    ushort_t* pw2b = (ushort_t*)alloc((size_t)DIMD * PHH * 2);
    ushort_t* w1vb = (ushort_t*)alloc((size_t)CC * 256 * 2);
    ushort_t* wsvb = (ushort_t*)alloc((size_t)CC * 256 * 2);
    ushort_t* w2vb = (ushort_t*)alloc((size_t)CC * CC * 2);
    ushort_t* wkb  = (ushort_t*)alloc((size_t)DIMD * CC * 2);
    ushort_t* wqb  = (ushort_t*)alloc((size_t)DIMD * CC * 2);
    ushort_t* wvb  = (ushort_t*)alloc((size_t)DIMD * CC * 2);
    ushort_t* sb16 = (ushort_t*)alloc(M * DIMD * 2);          //  67 MB
    // overlay: Rpart (67 MB, rg -> r_reduce lifetime only)
    char* ovl = (char*)alloc(M * DIMD * 2);                   //  67 MB
    float* Rpart = (float*)ovl;

    int ZN = 16 + 256;   // only stats+mu are accumulated; R is overwritten
    zero_kernel<<<2, 256, 0, stream>>>(zero0, ZN);
    knn_kernel<<<BB * NN, 256, 0, stream>>>(pos, idx);
    cvt_w_kernel<<<(720896 + 255) / 256, 256, 0, stream>>>(aw1, aw2, pw2, mlpv_w1, mlpv_ws, mlpv_w2,
                                                           wk, wq, wv, w1b, w2b, pw2b,
                                                           w1vb, wsvb, w2vb, wkb, wqb, wvb, w2f8);
    cvtx_kernel<<<dim3(NN / 64, BB), 256, 0, stream>>>(key, query, kqT);
    gemmvfull_kernel<<<(int)(P / 128), 256, 0, stream>>>(kqT, w1vb, wsvb, w2vb, wvb,
                                                         mlpv_b1, mlpv_b2, mlpv_bs, bv,
                                                         valueTf, vT);
    gemmkq_kernel<<<dim3(P / 128, 4), 256, 0, stream>>>(kqT, wkb, wqb, bk, bq, kT, qT);
    pos_stats_kernel<<<BB * NN * KK / 256, 256, 0, stream>>>(pos, idx, stats);
    pos_bn_kernel<<<1, 64, 0, stream>>>(stats, pw1, pb1, pg1, pbe1, posA);
    gemmS_kernel<<<dim3(M / 128, DIMD / 128), 256, 0, stream>>>(pos, idx, pw1, pb1, posA,
                                                                pw2b, pb2, sb16, qT, kT);
    rg_kernel<<<RSPLIT, 1024, 0, stream>>>(sb16, Rpart, mu);
    r_reduce_kernel<<<DIMD * DIMD / 256, 256, 0, stream>>>(Rpart, R);
    attn_bn_kernel<<<AHH, DIMD, 0, stream>>>(R, mu, aw1, ab1, ag1, abe1, attA);
    fused_mlp_kernel<<<(int)(M / 64), 256, 0, stream>>>(sb16, w1b, w2f8, attA, ab2, idx,
                                                        qT, kT, vT, we, be, valueTf, out);
}

// Round 11
// 611.357 us; speedup vs baseline: 1.0574x; 1.0574x over previous
//
#include <hip/hip_runtime.h>
#include <math.h>

#define BB 2
#define CC 128
#define NN 4096
#define KK 16
#define DIMD 256
#define PHH 64
#define AHH 1024
#define EPSF 1e-5f
#define RSPLIT 256
#define RKCH ((BB * NN * KK) / RSPLIT)   // 512 samples per R block (single-pass S)
#define LSTR 258    // LDS row stride (halfwords): conflict-free transposed gathers
#define KNN_CAP 512
#define FPT 8       // final_kernel points per thread

typedef unsigned short ushort_t;
typedef unsigned char uchar_t;
typedef unsigned long long u64;
typedef long long i64;
typedef __attribute__((ext_vector_type(8))) short short8;
typedef __attribute__((ext_vector_type(8))) unsigned short u16x8;
typedef __attribute__((ext_vector_type(4))) unsigned short u16x4;
typedef __attribute__((ext_vector_type(2))) unsigned short u16x2;
typedef __attribute__((ext_vector_type(4))) float f32x4;

__device__ __forceinline__ ushort_t f2b(float x) {
    union { float f; unsigned u; } v; v.f = x;
    unsigned r = v.u + 0x7fff + ((v.u >> 16) & 1);
    return (ushort_t)(r >> 16);
}
__device__ __forceinline__ float b2f(ushort_t x) {
    union { unsigned u; float f; } v; v.u = ((unsigned)x) << 16;
    return v.f;
}
__device__ __forceinline__ unsigned fsort(float x) {
    union { float f; unsigned u; } v; v.f = x;
    return v.u ^ ((v.u >> 31) ? 0xFFFFFFFFu : 0x80000000u);
}
__device__ __forceinline__ uchar_t f2f8(float x) {
    int p = __builtin_amdgcn_cvt_pk_fp8_f32(x, x, 0, false);
    return (uchar_t)(p & 0xFF);
}

#define GLDS16(gp, lp) __builtin_amdgcn_global_load_lds( \
    (const __attribute__((address_space(1))) void*)(gp), \
    (__attribute__((address_space(3))) void*)(lp), 16, 0, 0)

// ---------------- K0: zero scratch accumulators (only stats+mu; R is overwritten) ----
__global__ void zero_kernel(float* p, int n) {
    int i = blockIdx.x * blockDim.x + threadIdx.x;
    if (i < n) p[i] = 0.f;
}

// ---------------- K1: exact kNN via u64-key threshold select ----------------
__global__ __launch_bounds__(256) void knn_kernel(const float* __restrict__ pos,
                                                  int* __restrict__ idx) {
    int bid = blockIdx.x;
    int b = bid / NN, n = bid % NN;
    int t = threadIdx.x;
    int lane = t & 63, w = t >> 6;
    const float* px = pos + (size_t)b * 3 * NN;
    const float* py = px + NN;
    const float* pz = px + 2 * NN;
    float qx = px[n], qy = py[n], qz = pz[n];
    float qs = qx * qx + qy * qy + qz * qz;

    u64 keys[KK];
    u64 lmin = ~0ull;
#pragma unroll
    for (int j = 0; j < KK; ++j) {
        int m = t + 256 * j;
        float mx = px[m], my = py[m], mz = pz[m];
        float ms = mx * mx + my * my + mz * mz;
        float dt = qx * mx + qy * my + qz * mz;
        float d = qs + ms - 2.f * dt;
        u64 k = ((u64)fsort(d) << 32) | (unsigned)m;
        keys[j] = k;
        lmin = k < lmin ? k : lmin;
    }

    __shared__ u64 T0s[4];
    __shared__ u64 pool[KNN_CAP];
    __shared__ int cnt;

    u64 k = lmin, m4 = 0;
#pragma unroll
    for (int r = 0; r < 4; ++r) {
        u64 mv = k;
#pragma unroll
        for (int off = 32; off >= 1; off >>= 1) {
            u64 o = __shfl_xor(mv, off);
            mv = o < mv ? o : mv;
        }
        if (r == 3) m4 = mv;
        if (k == mv) k = ~0ull;
    }
    if (lane == 0) T0s[w] = m4;
    if (t == 0) cnt = 0;
    __syncthreads();
    u64 T0 = T0s[0];
    T0 = T0s[1] > T0 ? T0s[1] : T0;
    T0 = T0s[2] > T0 ? T0s[2] : T0;
    T0 = T0s[3] > T0 ? T0s[3] : T0;

#pragma unroll
    for (int j = 0; j < KK; ++j) {
        if (keys[j] <= T0) {
            int p = atomicAdd(&cnt, 1);
            if (p < KNN_CAP) pool[p] = keys[j];
        }
    }
    __syncthreads();
    int C = cnt < KNN_CAP ? cnt : KNN_CAP;
    if (t < C) {
        u64 me = pool[t];
        int r = 0;
        for (int i = 0; i < C; ++i) r += (pool[i] < me);
        if (r < KK) idx[(size_t)bid * KK + r] = (int)(me & 0xFFFFFFFFu);
    }
}

// ---------------- K2: transpose key/query -> kqT bf16 (8192 x 256) ----------------
__global__ __launch_bounds__(256) void cvtx_kernel(const float* __restrict__ key,
                                                   const float* __restrict__ query,
                                                   ushort_t* __restrict__ kqT) {
    __shared__ float xs[128][65];
    int b = blockIdx.y, n0 = blockIdx.x * 64, t = threadIdx.x;
    for (int h = 0; h < 2; ++h) {
        const float* src = (h ? query : key) + (size_t)b * CC * NN;
        if (h) __syncthreads();
#pragma unroll
        for (int it = 0; it < 32; ++it) {
            int l = it * 256 + t;
            xs[l >> 6][l & 63] = src[(size_t)(l >> 6) * NN + n0 + (l & 63)];
        }
        __syncthreads();
#pragma unroll
        for (int it = 0; it < 8; ++it) {
            int l = it * 256 + t;
            int row = l >> 5, c0 = (l & 31) * 4;
            u16x4 pk;
            pk[0] = f2b(xs[c0][row]);
            pk[1] = f2b(xs[c0 + 1][row]);
            pk[2] = f2b(xs[c0 + 2][row]);
            pk[3] = f2b(xs[c0 + 3][row]);
            *(u16x4*)(kqT + ((size_t)b * NN + n0 + row) * 256 + h * 128 + c0) = pk;
        }
    }
}

// ---------------- K3v: FUSED value chain — h1 -> value -> vT, one kernel ------
// 48KB LDS (hv16 overlays h1 then value; tile layout == GLDS layout -> bit-identical).
__global__ __launch_bounds__(256) void gemmvfull_kernel(const ushort_t* __restrict__ kqT,
                                                        const ushort_t* __restrict__ w1vb,
                                                        const ushort_t* __restrict__ wsvb,
                                                        const ushort_t* __restrict__ w2vb,
                                                        const ushort_t* __restrict__ wvb,
                                                        const float* __restrict__ b1,
                                                        const float* __restrict__ b2,
                                                        const float* __restrict__ bs,
                                                        const float* __restrict__ bv,
                                                        float* __restrict__ valueTf,
                                                        float* __restrict__ vT) {
    __shared__ ushort_t lA[128 * 32];
    __shared__ ushort_t lB[128 * 32];
    __shared__ ushort_t hv16[128 * 128];  // overlay: h1 (phases A/B), then value (B epi/C)
    int t = threadIdx.x, lane = t & 63, w = t >> 6;
    int wr = w >> 1, wc = w & 1;
    size_t row0 = (size_t)blockIdx.x * 128;
    int m16 = lane & 15, kg = lane >> 4;
    ushort_t* lA0 = lA + w * 512;
    ushort_t* lB0 = lB + w * 512;

    f32x4 acc[4][4];
#pragma unroll
    for (int i = 0; i < 4; ++i)
#pragma unroll
        for (int j = 0; j < 4; ++j) acc[i][j] = (f32x4){0.f, 0.f, 0.f, 0.f};

    // ---- phase A: h1 = relu(W1v·kq + b1), 128 rows x 128 ch, K=256 ----
    {
        const ushort_t* gA = kqT + (row0 + (size_t)w * 16 + m16) * 256 + kg * 8;
        const ushort_t* gB = w1vb + ((size_t)(w * 16 + m16)) * 256 + kg * 8;
        for (int kt = 0; kt < 8; ++kt) {
            int ko = kt * 32;
            GLDS16(gA + ko, lA0);
            GLDS16(gA + (size_t)64 * 256 + ko, lA0 + 2048);
            GLDS16(gB + ko, lB0);
            GLDS16(gB + (size_t)64 * 256 + ko, lB0 + 2048);
            __syncthreads();
            short8 af[4], bf[4];
#pragma unroll
            for (int i = 0; i < 4; ++i) {
                af[i] = *(const short8*)(lA + ((wr * 4 + i) * 512 + kg * 128 + m16 * 8));
                bf[i] = *(const short8*)(lB + ((wc * 4 + i) * 512 + kg * 128 + m16 * 8));
            }
#pragma unroll
            for (int i = 0; i < 4; ++i)
#pragma unroll
                for (int j = 0; j < 4; ++j)
                    acc[i][j] = __builtin_amdgcn_mfma_f32_16x16x32_bf16(af[i], bf[j], acc[i][j], 0, 0, 0);
            __syncthreads();
        }
#pragma unroll
        for (int j = 0; j < 4; ++j) {
            int c = wc * 64 + j * 16 + m16;
            float bi = b1[c];
            int win = c >> 5, cc = c & 31, kgp = cc >> 3, jp = cc & 7;
#pragma unroll
            for (int i = 0; i < 4; ++i) {
                int s = wr * 4 + i;
#pragma unroll
                for (int rg = 0; rg < 4; ++rg) {
                    int m16p = kg * 4 + rg;
                    hv16[win * 4096 + s * 512 + kgp * 128 + m16p * 8 + jp] =
                        f2b(fmaxf(acc[i][j][rg] + bi, 0.f));
                }
            }
        }
    }

    // ---- phase B: value = Ws·kq (K=256) + W2·h1 (K=128, LDS) + b2 + bs ----
#pragma unroll
    for (int i = 0; i < 4; ++i)
#pragma unroll
        for (int j = 0; j < 4; ++j) acc[i][j] = (f32x4){0.f, 0.f, 0.f, 0.f};
    {
        const ushort_t* gA = kqT + (row0 + (size_t)w * 16 + m16) * 256 + kg * 8;
        const ushort_t* gB = wsvb + ((size_t)(w * 16 + m16)) * 256 + kg * 8;
        for (int kt = 0; kt < 8; ++kt) {
            int ko = kt * 32;
            GLDS16(gA + ko, lA0);
            GLDS16(gA + (size_t)64 * 256 + ko, lA0 + 2048);
            GLDS16(gB + ko, lB0);
            GLDS16(gB + (size_t)64 * 256 + ko, lB0 + 2048);
            __syncthreads();
            short8 af[4], bf[4];
#pragma unroll
            for (int i = 0; i < 4; ++i) {
                af[i] = *(const short8*)(lA + ((wr * 4 + i) * 512 + kg * 128 + m16 * 8));
                bf[i] = *(const short8*)(lB + ((wc * 4 + i) * 512 + kg * 128 + m16 * 8));
            }
#pragma unroll
            for (int i = 0; i < 4; ++i)
#pragma unroll
                for (int j = 0; j < 4; ++j)
                    acc[i][j] = __builtin_amdgcn_mfma_f32_16x16x32_bf16(af[i], bf[j], acc[i][j], 0, 0, 0);
            __syncthreads();
        }
    }
    {
        const ushort_t* gB = w2vb + ((size_t)(w * 16 + m16)) * 128 + kg * 8;
        for (int kt = 0; kt < 4; ++kt) {
            int ko = kt * 32;
            GLDS16(gB + ko, lB0);
            GLDS16(gB + (size_t)64 * 128 + ko, lB0 + 2048);
            __syncthreads();
            short8 af[4], bf[4];
#pragma unroll
            for (int i = 0; i < 4; ++i) {
                af[i] = *(const short8*)(hv16 + (kt * 4096 + (wr * 4 + i) * 512 + kg * 128 + m16 * 8));
                bf[i] = *(const short8*)(lB + ((wc * 4 + i) * 512 + kg * 128 + m16 * 8));
            }
#pragma unroll
            for (int i = 0; i < 4; ++i)
#pragma unroll
                for (int j = 0; j < 4; ++j)
                    acc[i][j] = __builtin_amdgcn_mfma_f32_16x16x32_bf16(af[i], bf[j], acc[i][j], 0, 0, 0);
            __syncthreads();   // after the last iteration: ALL h1 reads drained
        }
    }
#pragma unroll
    for (int j = 0; j < 4; ++j) {
        int c = wc * 64 + j * 16 + m16;
        float bi = b2[c] + bs[c];
        int win = c >> 5, cc = c & 31, kgp = cc >> 3, jp = cc & 7;
#pragma unroll
        for (int i = 0; i < 4; ++i) {
            int s = wr * 4 + i;
#pragma unroll
            for (int rg = 0; rg < 4; ++rg) {
                float v = acc[i][j][rg] + bi;
                int m16p = kg * 4 + rg;
                valueTf[(row0 + s * 16 + m16p) * (size_t)CC + c] = v;
                hv16[win * 4096 + s * 512 + kgp * 128 + m16p * 8 + jp] = f2b(v);
            }
        }
    }
    __syncthreads();

    // ---- phase C: vT = value·wv^T + bv, two 128-col passes, K=128 (LDS) ----
    for (int pass = 0; pass < 2; ++pass) {
#pragma unroll
        for (int i = 0; i < 4; ++i)
#pragma unroll
            for (int j = 0; j < 4; ++j) acc[i][j] = (f32x4){0.f, 0.f, 0.f, 0.f};
        int col0 = pass * 128;
        const ushort_t* gB = wvb + ((size_t)(col0 + w * 16 + m16)) * 128 + kg * 8;
        for (int kt = 0; kt < 4; ++kt) {
            int ko = kt * 32;
            GLDS16(gB + ko, lB0);
            GLDS16(gB + (size_t)64 * 128 + ko, lB0 + 2048);
            __syncthreads();
            short8 af[4], bf[4];
#pragma unroll
            for (int i = 0; i < 4; ++i) {
                af[i] = *(const short8*)(hv16 + (kt * 4096 + (wr * 4 + i) * 512 + kg * 128 + m16 * 8));
                bf[i] = *(const short8*)(lB + ((wc * 4 + i) * 512 + kg * 128 + m16 * 8));
            }
#pragma unroll
            for (int i = 0; i < 4; ++i)
#pragma unroll
                for (int j = 0; j < 4; ++j)
                    acc[i][j] = __builtin_amdgcn_mfma_f32_16x16x32_bf16(af[i], bf[j], acc[i][j], 0, 0, 0);
            __syncthreads();
        }
#pragma unroll
        for (int j = 0; j < 4; ++j) {
            int n = col0 + wc * 64 + j * 16 + m16;
            float bi = bv[n];
#pragma unroll
            for (int i = 0; i < 4; ++i) {
                size_t r = row0 + wr * 64 + i * 16 + kg * 4;
#pragma unroll
                for (int rg = 0; rg < 4; ++rg)
                    vT[(r + rg) * (size_t)DIMD + n] = acc[i][j][rg] + bi;
            }
        }
    }
}

// ---------------- K3c: kT and qT in one launch ----------------
__global__ __launch_bounds__(256) void gemmkq_kernel(const ushort_t* __restrict__ kqT,
                                                     const ushort_t* __restrict__ wkb,
                                                     const ushort_t* __restrict__ wqb,
                                                     const float* __restrict__ bk,
                                                     const float* __restrict__ bq,
                                                     float* __restrict__ kT,
                                                     float* __restrict__ qT) {
    __shared__ ushort_t lA[128 * 32];
    __shared__ ushort_t lB[128 * 32];
    int half = blockIdx.y >> 1;
    int col0 = (blockIdx.y & 1) * 128;
    const ushort_t* A = kqT + half * 128;
    const ushort_t* Bm = half ? wqb : wkb;
    const float* bias = half ? bq : bk;
    float* outF = half ? qT : kT;

    int t = threadIdx.x, lane = t & 63, w = t >> 6;
    int wr = w >> 1, wc = w & 1;
    size_t row0 = (size_t)blockIdx.x * 128;
    int m16 = lane & 15, kg = lane >> 4;
    f32x4 acc[4][4];
#pragma unroll
    for (int i = 0; i < 4; ++i)
#pragma unroll
        for (int j = 0; j < 4; ++j) acc[i][j] = (f32x4){0.f, 0.f, 0.f, 0.f};
    const ushort_t* gA = A + (row0 + (size_t)w * 16 + m16) * 256 + kg * 8;
    const ushort_t* gB = Bm + ((size_t)(col0 + w * 16 + m16)) * 128 + kg * 8;
    ushort_t* lA0 = lA + w * 512;
    ushort_t* lB0 = lB + w * 512;
    for (int kt = 0; kt < 4; ++kt) {
        int ko = kt * 32;
        GLDS16(gA + ko, lA0);
        GLDS16(gA + (size_t)64 * 256 + ko, lA0 + 2048);
        GLDS16(gB + ko, lB0);
        GLDS16(gB + (size_t)64 * 128 + ko, lB0 + 2048);
        __syncthreads();
        short8 af[4], bf[4];
#pragma unroll
        for (int i = 0; i < 4; ++i) {
            af[i] = *(const short8*)(lA + ((wr * 4 + i) * 512 + kg * 128 + m16 * 8));
            bf[i] = *(const short8*)(lB + ((wc * 4 + i) * 512 + kg * 128 + m16 * 8));
        }
#pragma unroll
        for (int i = 0; i < 4; ++i)
#pragma unroll
            for (int j = 0; j < 4; ++j)
                acc[i][j] = __builtin_amdgcn_mfma_f32_16x16x32_bf16(af[i], bf[j], acc[i][j], 0, 0, 0);
        __syncthreads();
    }
#pragma unroll
    for (int j = 0; j < 4; ++j) {
        int n = col0 + wc * 64 + j * 16 + m16;
        float bi = bias[n];
#pragma unroll
        for (int i = 0; i < 4; ++i) {
            size_t r = row0 + wr * 64 + i * 16 + kg * 4;
#pragma unroll
            for (int rg = 0; rg < 4; ++rg)
                outF[(r + rg) * (size_t)DIMD + n] = acc[i][j][rg] + bi;
        }
    }
}

// ---------------- K5: pos_rel moments (wave-shfl reduce; 1 barrier) ----
__global__ __launch_bounds__(256) void pos_stats_kernel(const float* __restrict__ pos,
                                                        const int* __restrict__ idx,
                                                        float* __restrict__ stats) {
    int sid = blockIdx.x * 256 + threadIdx.x;
    int b = sid / (NN * KK);
    int r = sid % (NN * KK);
    int n = r / KK;
    int m = idx[sid];
    const float* px = pos + (size_t)b * 3 * NN;
    float dx = px[n] - px[m];
    float dy = px[NN + n] - px[NN + m];
    float dz = px[2 * NN + n] - px[2 * NN + m];
    float v[9] = {dx, dy, dz, dx * dx, dy * dy, dz * dz, dx * dy, dx * dz, dy * dz};
    __shared__ float lsum[4][9];
    int lane = threadIdx.x & 63, w = threadIdx.x >> 6;
#pragma unroll
    for (int j = 0; j < 9; ++j) {
        float x = v[j];
#pragma unroll
        for (int off = 32; off >= 1; off >>= 1) x += __shfl_xor(x, off);
        if (lane == 0) lsum[w][j] = x;
    }
    __syncthreads();
    if (threadIdx.x < 9) {
        float s = lsum[0][threadIdx.x] + lsum[1][threadIdx.x]
                + lsum[2][threadIdx.x] + lsum[3][threadIdx.x];
        atomicAdd(&stats[threadIdx.x], s);
    }
}

// ---------------- K6: pos BN affine (a1, a0) per 64 channels ----------------
__global__ void pos_bn_kernel(const float* __restrict__ stats, const float* __restrict__ pw1,
                              const float* __restrict__ pb1, const float* __restrict__ pg1,
                              const float* __restrict__ pbe1, float* __restrict__ posA) {
    int c = threadIdx.x;
    if (c >= PHH) return;
    float M = (float)(BB * NN * KK);
    float mu0 = stats[0] / M, mu1 = stats[1] / M, mu2 = stats[2] / M;
    float E00 = stats[3] / M, E11 = stats[4] / M, E22 = stats[5] / M;
    float E01 = stats[6] / M, E02 = stats[7] / M, E12 = stats[8] / M;
    float w0 = pw1[c * 3], w1 = pw1[c * 3 + 1], w2 = pw1[c * 3 + 2];
    float wmu = w0 * mu0 + w1 * mu1 + w2 * mu2;
    float mean_h = wmu + pb1[c];
    float Eh2 = w0 * w0 * E00 + w1 * w1 * E11 + w2 * w2 * E22
              + 2.f * (w0 * w1 * E01 + w0 * w2 * E02 + w1 * w2 * E12)
              + 2.f * pb1[c] * wmu + pb1[c] * pb1[c];
    float var = Eh2 - mean_h * mean_h;
    float a1 = pg1[c] * rsqrtf(var + EPSF);
    posA[c] = a1;
    posA[PHH + c] = pbe1[c] - mean_h * a1;
}

// ---------------- K9: R partials via MFMA (1024 thr, single-pass S, mu folded) ----
__global__ __launch_bounds__(1024) void rg_kernel(const ushort_t* __restrict__ S,
                                                  float* __restrict__ Rpart,
                                                  float* __restrict__ mu) {
    __shared__ ushort_t ls[32 * LSTR];
    __shared__ float fmu[DIMD];
    int t = threadIdx.x;
    int lane = t & 63, w = t >> 6;          // w 0..15
    int ti = w >> 3, tj = (w >> 2) & 1;     // quadrant
    int wr = (w >> 1) & 1, wc = w & 1;
    int m16 = lane & 15, kg = lane >> 4;
    size_t kbase = (size_t)blockIdx.x * RKCH;

    if (t < DIMD) fmu[t] = 0.f;

    f32x4 acc[4][4];
#pragma unroll
    for (int i = 0; i < 4; ++i)
#pragma unroll
        for (int j = 0; j < 4; ++j) acc[i][j] = (f32x4){0.f, 0.f, 0.f, 0.f};

    int lm = t >> 5;            // 0..31: k-row within chunk
    int lc = (t & 31) * 8;      // 8-chan octet
    const ushort_t* gS = S + (kbase + lm) * DIMD + lc;
    ushort_t* lp = ls + lm * LSTR + lc;
    float csum[8];
#pragma unroll
    for (int c = 0; c < 8; ++c) csum[c] = 0.f;

    for (int kt = 0; kt < RKCH / 32; ++kt) {
        u16x8 v = *(const u16x8*)(gS + (size_t)kt * 32 * DIMD);
        __syncthreads();
#pragma unroll
        for (int q = 0; q < 4; ++q)
            *(u16x2*)(lp + 2 * q) = (u16x2){v[2 * q], v[2 * q + 1]};
#pragma unroll
        for (int c = 0; c < 8; ++c) csum[c] += b2f(v[c]);
        __syncthreads();
        short8 af[4], bf[4];
#pragma unroll
        for (int i = 0; i < 4; ++i) {
            int chA = ti * 128 + wr * 64 + i * 16 + m16;
            int chB = tj * 128 + wc * 64 + i * 16 + m16;
#pragma unroll
            for (int j = 0; j < 8; ++j) {
                int k = kg * 8 + j;
                af[i][j] = (short)ls[k * LSTR + chA];
                bf[i][j] = (short)ls[k * LSTR + chB];
            }
        }
#pragma unroll
        for (int i = 0; i < 4; ++i)
#pragma unroll
            for (int j = 0; j < 4; ++j)
                acc[i][j] = __builtin_amdgcn_mfma_f32_16x16x32_bf16(af[i], bf[j], acc[i][j], 0, 0, 0);
    }

    float* rp = Rpart + (size_t)blockIdx.x * (DIMD * DIMD);
#pragma unroll
    for (int i = 0; i < 4; ++i) {
        int r0 = ti * 128 + wr * 64 + i * 16 + kg * 4;
#pragma unroll
        for (int j = 0; j < 4; ++j) {
            int cn = tj * 128 + wc * 64 + j * 16 + m16;
#pragma unroll
            for (int rg = 0; rg < 4; ++rg)
                rp[(size_t)(r0 + rg) * DIMD + cn] = acc[i][j][rg];
        }
    }

    __syncthreads();
#pragma unroll
    for (int c = 0; c < 8; ++c) atomicAdd(&fmu[lc + c], csum[c]);
    __syncthreads();
    if (t < DIMD) atomicAdd(&mu[t], fmu[t]);
}

// ---------------- K9b: reduce R partials ----------------
__global__ __launch_bounds__(256) void r_reduce_kernel(const float* __restrict__ Rpart,
                                                       float* __restrict__ R) {
    int e = blockIdx.x * 256 + threadIdx.x;
    float s = 0.f;
    for (int p = 0; p < RSPLIT; ++p) s += Rpart[(size_t)p * (DIMD * DIMD) + e];
    R[e] = s;
}

// ---------------- K10: attn BN -> fused scale/offset per hidden channel ----------------
__global__ __launch_bounds__(256) void attn_bn_kernel(const float* __restrict__ R,
                                                      const float* __restrict__ mu,
                                                      const float* __restrict__ aw1,
                                                      const float* __restrict__ ab1,
                                                      const float* __restrict__ ag1,
                                                      const float* __restrict__ abe1,
                                                      float* __restrict__ attA) {
    int c = blockIdx.x;
    int t = threadIdx.x;
    __shared__ float wsh[DIMD];
    __shared__ float red[DIMD];
    wsh[t] = aw1[(size_t)c * DIMD + t];
    __syncthreads();
    const float* Rr = R + (size_t)t * DIMD;
    float q = 0.f;
#pragma unroll 4
    for (int j = 0; j < DIMD; ++j) q += Rr[j] * wsh[j];
    red[t] = q * wsh[t];
    __syncthreads();
    for (int off = 128; off >= 1; off >>= 1) {
        if (t < off) red[t] += red[t + off];
        __syncthreads();
    }
    float wRw = red[0];
    __syncthreads();
    red[t] = wsh[t] * mu[t];
    __syncthreads();
    for (int off = 128; off >= 1; off >>= 1) {
        if (t < off) red[t] += red[t + off];
        __syncthreads();
    }
    if (t == 0) {
        float M = (float)(BB * NN * KK);
        float wmu = red[0] / M;
        float b1c = ab1[c];
        float Eh = wmu + b1c;
        float Eh2 = wRw / M + 2.f * b1c * wmu + b1c * b1c;
        float var = Eh2 - Eh * Eh;
        float a1 = ag1[c] * rsqrtf(var + EPSF);
        attA[c] = a1;
        attA[AHH + c] = a1 * b1c + abe1[c] - Eh * a1;
    }
}

// ---------------- K10b: convert all weights to bf16 (+ W2 to fp8 x64) ----------------
__global__ void cvt_w_kernel(const float* __restrict__ aw1, const float* __restrict__ aw2,
                             const float* __restrict__ pw2,
                             const float* __restrict__ mw1, const float* __restrict__ mws,
                             const float* __restrict__ mw2,
                             const float* __restrict__ wk, const float* __restrict__ wq,
                             const float* __restrict__ wv,
                             ushort_t* __restrict__ w1b, ushort_t* __restrict__ w2b,
                             ushort_t* __restrict__ pw2b,
                             ushort_t* __restrict__ w1vb, ushort_t* __restrict__ wsvb,
                             ushort_t* __restrict__ w2vb,
                             ushort_t* __restrict__ wkb, ushort_t* __restrict__ wqb,
                             ushort_t* __restrict__ wvb,
                             uchar_t* __restrict__ w2f8) {
    int i = blockIdx.x * 256 + threadIdx.x;
    int o = i;
    if (o < 262144) { w1b[o] = f2b(aw1[o]); return; }   o -= 262144;
    if (o < 262144) { w2b[o] = f2b(aw2[o]); w2f8[o] = f2f8(aw2[o] * 64.f); return; } o -= 262144;
    if (o < 16384)  { pw2b[o] = f2b(pw2[o]); return; }  o -= 16384;
    if (o < 32768)  { w1vb[o] = f2b(mw1[o]); return; }  o -= 32768;
    if (o < 32768)  { wsvb[o] = f2b(mws[o]); return; }  o -= 32768;
    if (o < 16384)  { w2vb[o] = f2b(mw2[o]); return; }  o -= 16384;
    if (o < 32768)  { wkb[o] = f2b(wk[o]); return; }    o -= 32768;
    if (o < 32768)  { wqb[o] = f2b(wq[o]); return; }    o -= 32768;
    if (o < 32768)  { wvb[o] = f2b(wv[o]); }
}

// ---------------- gemmS: s = q - k_g + (P1·pw2^T + pb2), P1 fused in-staging ----------
__global__ __launch_bounds__(256) void gemmS_kernel(const float* __restrict__ pos,
                                                    const int* __restrict__ gidx,
                                                    const float* __restrict__ pw1,
                                                    const float* __restrict__ pb1,
                                                    const float* __restrict__ posA,
                                                    const ushort_t* __restrict__ Bm,
                                                    const float* __restrict__ p0,
                                                    ushort_t* __restrict__ Sb,
                                                    const float* __restrict__ qT,
                                                    const float* __restrict__ kT) {
    __shared__ ushort_t lA[128 * 32];
    __shared__ ushort_t lB[128 * 32];
    __shared__ float ld3[128][4];    // dx,dy,dz per row (pad 4 for bank spread)
    __shared__ float pc[64][6];      // w0,w1,w2,b1,a1,a0 per hidden channel
    int t = threadIdx.x;
    int lane = t & 63, w = t >> 6;
    int wr = w >> 1, wc = w & 1;
    size_t row0 = (size_t)blockIdx.x * 128;
    int col0 = blockIdx.y * 128;
    int m16 = lane & 15, kg = lane >> 4;

    if (t < 64) {
        pc[t][0] = pw1[t * 3]; pc[t][1] = pw1[t * 3 + 1]; pc[t][2] = pw1[t * 3 + 2];
        pc[t][3] = pb1[t];     pc[t][4] = posA[t];        pc[t][5] = posA[PHH + t];
    }
    if (t < 128) {
        int row = (int)row0 + t;
        int m = gidx[row];
        int p = row >> 4;
        int b = p >> 12, n = p & (NN - 1);
        const float* px = pos + (size_t)b * 3 * NN;
        ld3[t][0] = px[n] - px[m];
        ld3[t][1] = px[NN + n] - px[NN + m];
        ld3[t][2] = px[2 * NN + n] - px[2 * NN + m];
    }

    f32x4 acc[4][4];
#pragma unroll
    for (int i = 0; i < 4; ++i)
#pragma unroll
        for (int j = 0; j < 4; ++j) acc[i][j] = (f32x4){0.f, 0.f, 0.f, 0.f};

    const ushort_t* gB = Bm + ((size_t)(col0 + w * 16 + m16)) * PHH + kg * 8;
    ushort_t* lB0 = lB + w * 512;
    __syncthreads();   // ld3/pc ready

    for (int kt = 0; kt < 2; ++kt) {
        int ko = kt * 32;
        GLDS16(gB + ko, lB0);
        GLDS16(gB + (size_t)64 * PHH + ko, lB0 + 2048);
#pragma unroll
        for (int half = 0; half < 2; ++half) {
            int rl = half * 64 + w * 16 + m16;
            float dx = ld3[rl][0], dy = ld3[rl][1], dz = ld3[rl][2];
            u16x8 pk;
#pragma unroll
            for (int j = 0; j < 8; ++j) {
                int c = ko + kg * 8 + j;
                float h = pc[c][0] * dx + pc[c][1] * dy + pc[c][2] * dz + pc[c][3];
                pk[j] = f2b(fmaxf(h * pc[c][4] + pc[c][5], 0.f));
            }
            *(u16x8*)(lA + w * 512 + half * 2048 + lane * 8) = pk;
        }
        __syncthreads();
        short8 af[4], bf[4];
#pragma unroll
        for (int i = 0; i < 4; ++i) {
            af[i] = *(const short8*)(lA + ((wr * 4 + i) * 512 + kg * 128 + m16 * 8));
            bf[i] = *(const short8*)(lB + ((wc * 4 + i) * 512 + kg * 128 + m16 * 8));
        }
#pragma unroll
        for (int i = 0; i < 4; ++i)
#pragma unroll
            for (int j = 0; j < 4; ++j)
                acc[i][j] = __builtin_amdgcn_mfma_f32_16x16x32_bf16(af[i], bf[j], acc[i][j], 0, 0, 0);
        __syncthreads();
    }

    int nn[4]; float bi[4];
#pragma unroll
    for (int j = 0; j < 4; ++j) { nn[j] = col0 + wc * 64 + j * 16 + m16; bi[j] = p0[nn[j]]; }
#pragma unroll
    for (int i = 0; i < 4; ++i) {
        size_t r = row0 + wr * 64 + i * 16 + kg * 4;
#pragma unroll
        for (int rg = 0; rg < 4; ++rg) {
            size_t rr = r + rg;
            int p = (int)(rr >> 4);
            int krow = (p & ~(NN - 1)) + gidx[rr];
            const float* qrow = qT + (size_t)p * DIMD;
            const float* kro = kT + (size_t)krow * DIMD;
#pragma unroll
            for (int j = 0; j < 4; ++j) {
                float sv = qrow[nn[j]] - kro[nn[j]] + acc[i][j][rg] + bi[j];
                Sb[rr * (size_t)DIMD + nn[j]] = f2b(sv);
            }
        }
    }
}

// ---------------- K11: fused attn MLP + softmax + aggregation (frozen) --------
// jc loop frozen (7 structural nulls). R10's final-fusion REVERTED: it inflated
// this kernel +50us (we re-read 64->268MB L2, serial tail phase on the critical
// path). R5's "absorbs work free" holds for scattered-latency work only.
__global__ __launch_bounds__(256, 3) void fused_mlp_kernel(const ushort_t* __restrict__ S,
                                                        const ushort_t* __restrict__ w1b,
                                                        const uchar_t* __restrict__ w2f8,
                                                        const float* __restrict__ attA,
                                                        const float* __restrict__ ab2,
                                                        const int* __restrict__ idx,
                                                        const float* __restrict__ qT,
                                                        const float* __restrict__ kT,
                                                        const float* __restrict__ vT,
                                                        float* __restrict__ aggT) {
    __shared__ char smem[49152];
    ushort_t* lS  = (ushort_t*)smem;             // 32 KB: 64 smp x 256 k bf16
    uchar_t*  lHt = (uchar_t*)(smem + 32768);    // 2 x 8 KB: 128 hid x 64 smp fp8, dbuf
    ushort_t* lgB = (ushort_t*)smem;             // epilogue overlay: 256 out x 64 smp, stride 72

    int t = threadIdx.x;
    int lane = t & 63, w = t >> 6;
    int m16 = lane & 15, kg = lane >> 4;
    size_t row0 = (size_t)blockIdx.x * 64;

#pragma unroll
    for (int i = 0; i < 8; ++i) {
        int lb = w * 8 + i;
        int kt = lb >> 2, st = lb & 3;
        const ushort_t* gp = S + (row0 + st * 16 + m16) * DIMD + kt * 32 + kg * 8;
        GLDS16(gp, lS + lb * 512);
    }

    f32x4 acc2[4][4];
#pragma unroll
    for (int i = 0; i < 4; ++i)
#pragma unroll
        for (int j = 0; j < 4; ++j) acc2[i][j] = (f32x4){0.f, 0.f, 0.f, 0.f};

    __syncthreads();

    for (int jc = 0; jc < 8; ++jc) {
        uchar_t* lHb = lHt + (jc & 1) * 8192;
        f32x4 acc1[2][4];
#pragma unroll
        for (int hi = 0; hi < 2; ++hi)
#pragma unroll
            for (int sj = 0; sj < 4; ++sj) acc1[hi][sj] = (f32x4){0.f, 0.f, 0.f, 0.f};
        const ushort_t* wrow = w1b + ((size_t)(jc * 128 + w * 32 + m16)) * DIMD + kg * 8;
#pragma unroll
        for (int kt = 0; kt < 8; ++kt) {
            short8 af[2], bf[4];
            af[0] = *(const short8*)(wrow + kt * 32);
            af[1] = *(const short8*)(wrow + (size_t)16 * DIMD + kt * 32);
#pragma unroll
            for (int sj = 0; sj < 4; ++sj)
                bf[sj] = *(const short8*)(lS + (kt * 4 + sj) * 512 + kg * 128 + m16 * 8);
            __builtin_amdgcn_s_setprio(1);
#pragma unroll
            for (int hi = 0; hi < 2; ++hi)
#pragma unroll
                for (int sj = 0; sj < 4; ++sj)
                    acc1[hi][sj] = __builtin_amdgcn_mfma_f32_16x16x32_bf16(af[hi], bf[sj], acc1[hi][sj], 0, 0, 0);
            __builtin_amdgcn_s_setprio(0);
        }
#pragma unroll
        for (int hi = 0; hi < 2; ++hi) {
            float4 sc4 = *(const float4*)(attA + jc * 128 + w * 32 + hi * 16 + kg * 4);
            float4 of4 = *(const float4*)(attA + AHH + jc * 128 + w * 32 + hi * 16 + kg * 4);
#pragma unroll
            for (int sj = 0; sj < 4; ++sj) {
                float h0 = fmaxf(sc4.x * acc1[hi][sj][0] + of4.x, 0.f);
                float h1 = fmaxf(sc4.y * acc1[hi][sj][1] + of4.y, 0.f);
                float h2 = fmaxf(sc4.z * acc1[hi][sj][2] + of4.z, 0.f);
                float h3 = fmaxf(sc4.w * acc1[hi][sj][3] + of4.w, 0.f);
                int p01 = __builtin_amdgcn_cvt_pk_fp8_f32(h0, h1, 0, false);
                int pk = __builtin_amdgcn_cvt_pk_fp8_f32(h2, h3, p01, true);
                int ah = (w * 4 + sj) * 512 + (hi * 2 + (kg >> 1)) * 128 + m16 * 8 + (kg & 1) * 4;
                *(int*)(lHb + ah) = pk;
            }
        }
        __syncthreads();
#pragma unroll
        for (int gh = 0; gh < 2; ++gh) {
            i64 af2[8];
#pragma unroll
            for (int gq = 0; gq < 2; ++gq)
#pragma unroll
                for (int oi = 0; oi < 4; ++oi)
                    af2[gq * 4 + oi] = *(const i64*)(w2f8 + ((size_t)(w * 64 + oi * 16 + m16)) * AHH + jc * 128 + (gh * 2 + gq) * 32 + kg * 8);
#pragma unroll
            for (int gq = 0; gq < 2; ++gq) {
                i64 bf2[4];
#pragma unroll
                for (int sj = 0; sj < 4; ++sj)
                    bf2[sj] = *(const i64*)(lHb + ((gh * 2 + gq) * 4 + sj) * 512 + kg * 128 + m16 * 8);
                __builtin_amdgcn_s_setprio(1);
#pragma unroll
                for (int oi = 0; oi < 4; ++oi)
#pragma unroll
                    for (int sj = 0; sj < 4; ++sj)
                        acc2[oi][sj] = __builtin_amdgcn_mfma_f32_16x16x32_fp8_fp8(af2[gq * 4 + oi], bf2[sj], acc2[oi][sj], 0, 0, 0);
                __builtin_amdgcn_s_setprio(0);
            }
        }
    }
    __syncthreads();

    // phase 1: logits (acc2/64 + b2) -> lgB[out][smp] (bf16, stride 72)
    const float invsc = 0.015625f;
#pragma unroll
    for (int oi = 0; oi < 4; ++oi) {
        int ob = w * 64 + oi * 16 + kg * 4;
        float4 b2v = *(const float4*)(ab2 + ob);
#pragma unroll
        for (int sj = 0; sj < 4; ++sj) {
            int smp = sj * 16 + m16;
            lgB[(ob + 0) * 72 + smp] = f2b(acc2[oi][sj][0] * invsc + b2v.x);
            lgB[(ob + 1) * 72 + smp] = f2b(acc2[oi][sj][1] * invsc + b2v.y);
            lgB[(ob + 2) * 72 + smp] = f2b(acc2[oi][sj][2] * invsc + b2v.z);
            lgB[(ob + 3) * 72 + smp] = f2b(acc2[oi][sj][3] * invsc + b2v.w);
        }
    }
    __syncthreads();

    // phase 2: thread t owns out-channel t; 4 points; serial softmax in regs.
    int out = t;
    for (int pt = 0; pt < 4; ++pt) {
        int pid = (int)(row0 >> 4) + pt;
        u16x8 v0 = *(const u16x8*)(lgB + out * 72 + pt * 16);
        u16x8 v1 = *(const u16x8*)(lgB + out * 72 + pt * 16 + 8);
        float lg[KK];
#pragma unroll
        for (int s = 0; s < 8; ++s) { lg[s] = b2f(v0[s]); lg[s + 8] = b2f(v1[s]); }
        float mx = lg[0];
#pragma unroll
        for (int s = 1; s < KK; ++s) mx = fmaxf(mx, lg[s]);
        float se = 0.f;
#pragma unroll
        for (int s = 0; s < KK; ++s) { lg[s] = expf(lg[s] - mx); se += lg[s]; }
        float inv = 1.f / se;
        int base = pid & ~(NN - 1);
        float acc = 0.f;
#pragma unroll
        for (int s = 0; s < KK; ++s) {
            int row = pid * KK + s;
            int krow = base + idx[row];
            float sv = b2f(S[(size_t)row * DIMD + out]);
            float kv = kT[(size_t)krow * DIMD + out];
            acc += lg[s] * (sv + kv);
        }
        float vf = vT[(size_t)pid * DIMD + out];
        float q  = qT[(size_t)pid * DIMD + out];
        aggT[(size_t)pid * DIMD + out] = vf - q + acc * inv;
    }
}

// ---------------- K12: y = we·agg + be + value (both LDS-staged, coalesced) --------
__global__ __launch_bounds__(256) void final_kernel(const float* __restrict__ aggT,
                                                    const float* __restrict__ we,
                                                    const float* __restrict__ be,
                                                    const float* __restrict__ valueTf,
                                                    float* __restrict__ out) {
    __shared__ float xs[2 * FPT][DIMD];
    __shared__ float vs[2 * FPT][CC];
    int b = blockIdx.y;
    int n0 = blockIdx.x * (2 * FPT);
    int t = threadIdx.x;
    const float4* src = (const float4*)(aggT + ((size_t)b * NN + n0) * DIMD);
    float4* dst = (float4*)xs;
#pragma unroll
    for (int l = 0; l < (2 * FPT * DIMD / 4) / 256; ++l) dst[t + 256 * l] = src[t + 256 * l];
    const float4* src2 = (const float4*)(valueTf + ((size_t)b * NN + n0) * CC);
    float4* dst2 = (float4*)vs;
#pragma unroll
    for (int l = 0; l < (2 * FPT * CC / 4) / 256; ++l) dst2[t + 256 * l] = src2[t + 256 * l];
    __syncthreads();
    int o = t & 127, ph = t >> 7;
    float acc[FPT];
#pragma unroll
    for (int p = 0; p < FPT; ++p) acc[p] = 0.f;
    const float4* wr = (const float4*)(we + (size_t)o * DIMD);
#pragma unroll 8
    for (int i4 = 0; i4 < DIMD / 4; ++i4) {
        float4 w4 = wr[i4];
#pragma unroll
        for (int p = 0; p < FPT; ++p) {
            float4 x4 = *(const float4*)&xs[ph * FPT + p][i4 * 4];
            acc[p] += w4.x * x4.x + w4.y * x4.y + w4.z * x4.z + w4.w * x4.w;
        }
    }
    float bo = be[o];
#pragma unroll
    for (int p = 0; p < FPT; ++p) {
        size_t oi = ((size_t)b * CC + o) * NN + n0 + ph * FPT + p;
        out[oi] = acc[p] + bo + vs[ph * FPT + p][o];
    }
}

extern "C" void kernel_launch(void* const* d_in, const int* in_sizes, int n_in,
                              void* d_out, int out_size, void* d_ws, size_t ws_size,
                              hipStream_t stream) {
    (void)in_sizes; (void)n_in; (void)out_size; (void)ws_size;
    const float* pos     = (const float*)d_in[0];
    const float* key     = (const float*)d_in[1];
    const float* query   = (const float*)d_in[2];
    const float* mlpv_w1 = (const float*)d_in[3];
    const float* mlpv_b1 = (const float*)d_in[4];
    const float* mlpv_w2 = (const float*)d_in[5];
    const float* mlpv_b2 = (const float*)d_in[6];
    const float* mlpv_ws = (const float*)d_in[7];
    const float* mlpv_bs = (const float*)d_in[8];
    const float* wk  = (const float*)d_in[9];
    const float* bk  = (const float*)d_in[10];
    const float* wq  = (const float*)d_in[11];
    const float* bq  = (const float*)d_in[12];
    const float* wv  = (const float*)d_in[13];
    const float* bv  = (const float*)d_in[14];
    const float* pw1 = (const float*)d_in[15];
    const float* pb1 = (const float*)d_in[16];
    const float* pg1 = (const float*)d_in[17];
    const float* pbe1= (const float*)d_in[18];
    const float* pw2 = (const float*)d_in[19];
    const float* pb2 = (const float*)d_in[20];
    const float* aw1 = (const float*)d_in[21];
    const float* ab1 = (const float*)d_in[22];
    const float* ag1 = (const float*)d_in[23];
    const float* abe1= (const float*)d_in[24];
    const float* aw2 = (const float*)d_in[25];
    const float* ab2 = (const float*)d_in[26];
    const float* we  = (const float*)d_in[27];
    const float* be  = (const float*)d_in[28];
    float* out = (float*)d_out;

    char* wsb = (char*)d_ws;
    size_t off = 0;
    auto alloc = [&](size_t bytes) {
        void* p = wsb + off;
        off += (bytes + 255) & ~(size_t)255;
        return p;
    };
    const size_t M = (size_t)BB * NN * KK;   // 131072 rows
    const size_t P = (size_t)BB * NN;        // 8192 points
    int*   idx   = (int*)  alloc(M * 4);
    ushort_t* kqT     = (ushort_t*)alloc(P * 256 * 2);
    float*    valueTf = (float*)   alloc(P * CC * 4);
    float* kT    = (float*)alloc(P * DIMD * 4);
    float* qT    = (float*)alloc(P * DIMD * 4);
    float* vT    = (float*)alloc(P * DIMD * 4);
    float* aggT  = (float*)alloc(P * DIMD * 4);
    float* zero0 = (float*)alloc((size_t)(16 + 256 + 65536) * 4);
    float* stats = zero0;
    float* mu    = zero0 + 16;
    float* R     = zero0 + 16 + 256;
    float* posA  = (float*)alloc((size_t)2 * PHH * 4);
    float* attA  = (float*)alloc((size_t)2 * AHH * 4);
    ushort_t* w1b  = (ushort_t*)alloc((size_t)AHH * DIMD * 2);
    ushort_t* w2b  = (ushort_t*)alloc((size_t)DIMD * AHH * 2);
    uchar_t*  w2f8 = (uchar_t*) alloc((size_t)DIMD * AHH);
    ushort_t* pw2b = (ushort_t*)alloc((size_t)DIMD * PHH * 2);
    ushort_t* w1vb = (ushort_t*)alloc((size_t)CC * 256 * 2);
    ushort_t* wsvb = (ushort_t*)alloc((size_t)CC * 256 * 2);
    ushort_t* w2vb = (ushort_t*)alloc((size_t)CC * CC * 2);
    ushort_t* wkb  = (ushort_t*)alloc((size_t)DIMD * CC * 2);
    ushort_t* wqb  = (ushort_t*)alloc((size_t)DIMD * CC * 2);
    ushort_t* wvb  = (ushort_t*)alloc((size_t)DIMD * CC * 2);
    ushort_t* sb16 = (ushort_t*)alloc(M * DIMD * 2);          //  67 MB
    // overlay: Rpart (67 MB, rg -> r_reduce lifetime only)
    char* ovl = (char*)alloc(M * DIMD * 2);                   //  67 MB
    float* Rpart = (float*)ovl;

    int ZN = 16 + 256;   // only stats+mu are accumulated; R is overwritten
    zero_kernel<<<2, 256, 0, stream>>>(zero0, ZN);
    knn_kernel<<<BB * NN, 256, 0, stream>>>(pos, idx);
    cvt_w_kernel<<<(720896 + 255) / 256, 256, 0, stream>>>(aw1, aw2, pw2, mlpv_w1, mlpv_ws, mlpv_w2,
                                                           wk, wq, wv, w1b, w2b, pw2b,
                                                           w1vb, wsvb, w2vb, wkb, wqb, wvb, w2f8);
    cvtx_kernel<<<dim3(NN / 64, BB), 256, 0, stream>>>(key, query, kqT);
    gemmvfull_kernel<<<(int)(P / 128), 256, 0, stream>>>(kqT, w1vb, wsvb, w2vb, wvb,
                                                         mlpv_b1, mlpv_b2, mlpv_bs, bv,
                                                         valueTf, vT);
    gemmkq_kernel<<<dim3(P / 128, 4), 256, 0, stream>>>(kqT, wkb, wqb, bk, bq, kT, qT);
    pos_stats_kernel<<<BB * NN * KK / 256, 256, 0, stream>>>(pos, idx, stats);
    pos_bn_kernel<<<1, 64, 0, stream>>>(stats, pw1, pb1, pg1, pbe1, posA);
    gemmS_kernel<<<dim3(M / 128, DIMD / 128), 256, 0, stream>>>(pos, idx, pw1, pb1, posA,
                                                                pw2b, pb2, sb16, qT, kT);
    rg_kernel<<<RSPLIT, 1024, 0, stream>>>(sb16, Rpart, mu);
    r_reduce_kernel<<<DIMD * DIMD / 256, 256, 0, stream>>>(Rpart, R);
    attn_bn_kernel<<<AHH, DIMD, 0, stream>>>(R, mu, aw1, ab1, ag1, abe1, attA);
    fused_mlp_kernel<<<(int)(M / 64), 256, 0, stream>>>(sb16, w1b, w2f8, attA, ab2, idx, qT, kT, vT, aggT);
    final_kernel<<<dim3(NN / (2 * FPT), BB), 256, 0, stream>>>(aggT, we, be, valueTf, out);
}